// Round 5
// baseline (439.592 us; speedup 1.0000x reference)
//
#include <hip/hip_runtime.h>

// ContinuousGameOfLife: x (16, 2048, 2048) f32 -> out same shape.
// around = 3x3 wrap-stencil sum minus center; smooth B3/S23 rule.
// Memory-bound target: ~528 MiB actual traffic -> ~87 us floor at 6.3 TB/s.
//
// R5 == R3/R4 resubmitted verbatim (both benches failed with
// GPUAcquisitionTimeout; no kernel data). Changes vs R2 (435.6us):
//  - RPT 16 -> 64: vertical read amplification 1.125 -> 1.031 (-24 MiB reads).
//    Grid (2,32,16) = 1024 blocks = 16 waves/CU; fills hit 82% peak BW at 10%
//    occupancy, so 50% occupancy is ample for streaming. (R1's RPT regression
//    is attributed to its nt-store confound: nt bypasses L2 write-combining.)
//  - Column halos via wave shuffle instead of scalar loads: l/r neighbors are
//    lane-adjacent register values (__shfl_up/down); only lanes 0 and 63 do a
//    masked scalar load. Read requests per wave-row drop 3x -> 1 (+2 masked).
//  - Keeps R2's collapsed rule (1 exp + 1 rcp, constants scaled 2^-40).

#define GOL_H 2048
#define GOL_W 2048
#define GOL_B 16
#define RPT 64            // rows per thread: read amplification (RPT+2)/RPT = 1.031
#define BLOCK 256         // threads per block; each thread owns 4 consecutive cols

// Constants for the collapsed rule (all scaled by 2^-40):
//   C15 = e^15 * 2^-40, C25 = e^25 * 2^-40, C35 = e^35 * 2^-40
#define LOG2E10 14.426950408889634f   // 10/ln(2)
#define C15 2.9731544e-06f
#define C25 0.06548808f
#define C35 1442.4719f
#define C2515 0.06548511f             // C25 - C15

__device__ __forceinline__ float game_rule(float cell, float a) {
    float t = __builtin_fmaf(LOG2E10, a, -40.0f);   // log2(u * 2^-40)
    t = fminf(t, 35.0f);                            // clamp: u <= 2^75
    float w = __builtin_amdgcn_exp2f(t);            // u * 2^-40
    float p = w + C15;                              // (u+e15) * 2^-40
    float q = w + C25;                              // (u+e25) * 2^-40
    float r = w + C35;                              // (u+e35) * 2^-40
    float f = __builtin_fmaf(cell, C2515, p);       // (u + e15 + cell*(e25-e15)) * 2^-40
    float num = C35 * w * f;
    float den = p * q * r;
    return num * __builtin_amdgcn_rcpf(den);
}

// Load one input row segment: aligned float4 at c0; column halos come from
// neighboring lanes via shuffle (masked scalar loads only at wave edges).
__device__ __forceinline__ void load_row(const float* __restrict__ row, int c0,
                                         int cl, int cr, int lane,
                                         float4& t, float4& v) {
    v = *(const float4*)(row + c0);
    float l = __shfl_up(v.w, 1);     // lane i-1's v.w == col c0-1
    float r = __shfl_down(v.x, 1);   // lane i+1's v.x == col c0+4
    if (lane == 0)  l = row[cl];     // wave-left edge: wrap/cross-wave column
    if (lane == 63) r = row[cr];     // wave-right edge
    t.x = l   + v.x + v.y;
    t.y = v.x + v.y + v.z;
    t.z = v.y + v.z + v.w;
    t.w = v.z + v.w + r;
}

__global__ __launch_bounds__(BLOCK)
void gol_kernel(const float* __restrict__ x, float* __restrict__ out) {
    const int b    = blockIdx.z;
    const int lane = threadIdx.x & 63;
    const int c0 = (blockIdx.x * BLOCK + threadIdx.x) * 4;   // first of 4 columns
    const int r0 = blockIdx.y * RPT;
    const int cl = (c0 - 1) & (GOL_W - 1);
    const int cr = (c0 + 4) & (GOL_W - 1);

    const float* xp = x   + (size_t)b * GOL_H * GOL_W;
    float*       op = out + (size_t)b * GOL_H * GOL_W;

    float4 tp, tc, tn, vc, vn, vdummy;

    // prime rows r0-1 (wrap) and r0
    load_row(xp + (size_t)((r0 - 1) & (GOL_H - 1)) * GOL_W, c0, cl, cr, lane, tp, vdummy);
    load_row(xp + (size_t)r0 * GOL_W,                       c0, cl, cr, lane, tc, vc);

#pragma unroll 4
    for (int i = 0; i < RPT; ++i) {
        const int r = r0 + i;
        load_row(xp + (size_t)((r + 1) & (GOL_H - 1)) * GOL_W, c0, cl, cr, lane, tn, vn);

        float4 o;
        o.x = game_rule(vc.x, tp.x + tc.x + tn.x - vc.x);
        o.y = game_rule(vc.y, tp.y + tc.y + tn.y - vc.y);
        o.z = game_rule(vc.z, tp.z + tc.z + tn.z - vc.z);
        o.w = game_rule(vc.w, tp.w + tc.w + tn.w - vc.w);

        *(float4*)(op + (size_t)r * GOL_W + c0) = o;

        tp = tc; tc = tn; vc = vn;
    }
}

extern "C" void kernel_launch(void* const* d_in, const int* in_sizes, int n_in,
                              void* d_out, int out_size, void* d_ws, size_t ws_size,
                              hipStream_t stream) {
    const float* x = (const float*)d_in[0];
    float* out = (float*)d_out;

    // grid: x over column strips (2048 / (4*256) = 2), y over row chunks, z over batch
    dim3 grid(GOL_W / (4 * BLOCK), GOL_H / RPT, GOL_B);
    dim3 block(BLOCK);
    gol_kernel<<<grid, block, 0, stream>>>(x, out);
}

// Round 7
// 436.441 us; speedup vs baseline: 1.0072x; 1.0072x over previous
//
#include <hip/hip_runtime.h>

// ContinuousGameOfLife: x (16, 2048, 2048) f32 -> out same shape.
// around = 3x3 wrap-stencil sum minus center; smooth B3/S23 rule.
// Memory-bound: 544 MiB actual traffic; kernel ~105us at the ~5.4 TB/s
// mixed read+write stream rate (86% of the 6.29 TB/s D2D copy ceiling).
//
// R7 == R6 resubmitted verbatim (R6 bench failed: GPUAcquisitionTimeout).
// R6 == R2 restored verbatim (best measured: 435.6us).
//   R1 (RPT=32 + nt-stores)      -> 452.5us  REGRESSED (nt bypasses L2 WC)
//   R5 (RPT=64 + shuffle halos)  -> 439.6us  REGRESSED (DS ops on crit path,
//                                             masked edge loads still issue)
// Conclusion: kernel is achieved-BW-limited, not byte-limited; RPT=16 with
// plain scalar halo loads is the best structure found.
//  - game_rule collapsed to 1 exp + 1 rcp (R2):
//      u = e^{10a}:  result = e35*u*(u+e15+cell*(e25-e15))
//                             / [(u+e15)(u+e25)(u+e35)]
//    constants pre-scaled by 2^-40; exp arg clamped so u <= 2^75.

#define GOL_H 2048
#define GOL_W 2048
#define GOL_B 16
#define RPT 16            // rows per thread: read amplification (RPT+2)/RPT = 1.125
#define BLOCK 256         // threads per block; each thread owns 4 consecutive cols

// Constants for the collapsed rule (all scaled by 2^-40):
//   C15 = e^15 * 2^-40, C25 = e^25 * 2^-40, C35 = e^35 * 2^-40
#define LOG2E10 14.426950408889634f   // 10/ln(2)
#define C15 2.9731544e-06f
#define C25 0.06548808f
#define C35 1442.4719f
#define C2515 0.06548511f             // C25 - C15

__device__ __forceinline__ float game_rule(float cell, float a) {
    float t = __builtin_fmaf(LOG2E10, a, -40.0f);   // log2(u * 2^-40)
    t = fminf(t, 35.0f);                            // clamp: u <= 2^75
    float w = __builtin_amdgcn_exp2f(t);            // u * 2^-40
    float p = w + C15;                              // (u+e15) * 2^-40
    float q = w + C25;                              // (u+e25) * 2^-40
    float r = w + C35;                              // (u+e35) * 2^-40
    float f = __builtin_fmaf(cell, C2515, p);       // (u + e15 + cell*(e25-e15)) * 2^-40
    float num = C35 * w * f;
    float den = p * q * r;
    return num * __builtin_amdgcn_rcpf(den);
}

// Load one input row segment: aligned float4 at c0 plus wrap-indexed scalar halos.
// Returns triple-sums t (horizontal 3-sums for the 4 columns) and raw center v.
__device__ __forceinline__ void load_row(const float* __restrict__ row, int c0,
                                         int cl, int cr, float4& t, float4& v) {
    v = *(const float4*)(row + c0);
    float l = row[cl];
    float r = row[cr];
    t.x = l   + v.x + v.y;
    t.y = v.x + v.y + v.z;
    t.z = v.y + v.z + v.w;
    t.w = v.z + v.w + r;
}

__global__ __launch_bounds__(BLOCK)
void gol_kernel(const float* __restrict__ x, float* __restrict__ out) {
    const int b  = blockIdx.z;
    const int c0 = (blockIdx.x * BLOCK + threadIdx.x) * 4;   // first of 4 columns
    const int r0 = blockIdx.y * RPT;
    const int cl = (c0 - 1) & (GOL_W - 1);
    const int cr = (c0 + 4) & (GOL_W - 1);

    const float* xp = x   + (size_t)b * GOL_H * GOL_W;
    float*       op = out + (size_t)b * GOL_H * GOL_W;

    float4 tp, tc, tn, vc, vn, vdummy;

    // prime rows r0-1 (wrap) and r0
    load_row(xp + (size_t)((r0 - 1) & (GOL_H - 1)) * GOL_W, c0, cl, cr, tp, vdummy);
    load_row(xp + (size_t)r0 * GOL_W,                       c0, cl, cr, tc, vc);

#pragma unroll 4
    for (int i = 0; i < RPT; ++i) {
        const int r = r0 + i;
        load_row(xp + (size_t)((r + 1) & (GOL_H - 1)) * GOL_W, c0, cl, cr, tn, vn);

        float4 o;
        o.x = game_rule(vc.x, tp.x + tc.x + tn.x - vc.x);
        o.y = game_rule(vc.y, tp.y + tc.y + tn.y - vc.y);
        o.z = game_rule(vc.z, tp.z + tc.z + tn.z - vc.z);
        o.w = game_rule(vc.w, tp.w + tc.w + tn.w - vc.w);

        *(float4*)(op + (size_t)r * GOL_W + c0) = o;

        tp = tc; tc = tn; vc = vn;
    }
}

extern "C" void kernel_launch(void* const* d_in, const int* in_sizes, int n_in,
                              void* d_out, int out_size, void* d_ws, size_t ws_size,
                              hipStream_t stream) {
    const float* x = (const float*)d_in[0];
    float* out = (float*)d_out;

    // grid: x over column strips (2048 / (4*256) = 2), y over row chunks, z over batch
    dim3 grid(GOL_W / (4 * BLOCK), GOL_H / RPT, GOL_B);
    dim3 block(BLOCK);
    gol_kernel<<<grid, block, 0, stream>>>(x, out);
}